// Round 8
// baseline (260.845 us; speedup 1.0000x reference)
//
#include <hip/hip_runtime.h>
#include <hip/hip_bf16.h>

#define NB 16
#define C 256
#define C4 64
#define HDIM 128
#define WDIM 128
#define HW 16384

typedef __bf16 bf16x8 __attribute__((ext_vector_type(8)));
typedef float f32x4 __attribute__((ext_vector_type(4)));

__device__ __forceinline__ unsigned short f2bf(float x) {
    union { __bf16 h; unsigned short u; } c;
    c.h = (__bf16)x;                       // RNE
    return c.u;
}
__device__ __forceinline__ float bf2f(unsigned short b) {
    union { float f; unsigned u; } a; a.u = ((unsigned)b) << 16; return a.f;
}

// ---------------------------------------------------------------------------
// K0: pack conv_w (64x256) and fuse_w (256x64) into MFMA fragment order,
// compute fuse_b_eff[c] = fuse_b[c] + sum_o fuse_w[c][o]*dw_b[o], and zero
// the g-sum accumulator (K1 atomically accumulates pool sums into it).
// Fragment (16x16x32): lane = (i&15) | (((k>>3)&3)<<4), e = k&7. The same
// packed data serves as A-frag of W and B-frag of W^T (layouts are
// transpose-symmetric), which is what lets K1/K3 swap mfma operands freely.
// ---------------------------------------------------------------------------
__global__ __launch_bounds__(256) void k0_pack(
    const float* __restrict__ conv_w, const float* __restrict__ fuse_w,
    const float* __restrict__ fuse_b, const float* __restrict__ dw_b,
    unsigned short* __restrict__ cwpk, unsigned short* __restrict__ fwpk,
    float* __restrict__ fbe, float* __restrict__ gsum)
{
    int tid = blockIdx.x * 256 + threadIdx.x;   // 0..16383
    {   // conv_w: M=64, K=256
        int m = tid >> 8, k = tid & 255;
        int frag = (m >> 4) * 8 + (k >> 5);
        int lane = (m & 15) | (((k >> 3) & 3) << 4);
        int e = k & 7;
        cwpk[(frag * 64 + lane) * 8 + e] = f2bf(conv_w[m * 256 + k]);
    }
    {   // fuse_w: M=256, K=64
        int m = tid >> 6, k = tid & 63;
        int frag = (m >> 4) * 2 + (k >> 5);
        int lane = (m & 15) | (((k >> 3) & 3) << 4);
        int e = k & 7;
        fwpk[(frag * 64 + lane) * 8 + e] = f2bf(fuse_w[m * 64 + k]);
    }
    if (tid < 256) {
        float s = fuse_b[tid];
        #pragma unroll
        for (int o = 0; o < 64; ++o) s += fuse_w[tid * 64 + o] * dw_b[o];
        fbe[tid] = s;
    }
    if (tid < NB * C4 * 9) gsum[tid] = 0.f;     // 9216 floats
}

// ---------------------------------------------------------------------------
// K1: f = conv1(x) + conv_b  (GEMM, operand-swapped: D^T = x^T . conv_w^T so
// each lane holds 4 CONSECUTIVE PIXELS of one o-channel -> dwordx2 f-stores).
// Also accumulates the adaptive-pool bin sums of f for this row into gsum
// via masked per-lane sums + shfl_xor reduce + atomicAdd (replaces K2).
// ---------------------------------------------------------------------------
__global__ __launch_bounds__(256) void k1_conv(
    const float* __restrict__ x, const unsigned short* __restrict__ cwpk,
    const float* __restrict__ conv_b, unsigned short* __restrict__ f_ws,
    float* __restrict__ gsum)
{
    __shared__ unsigned short xlds[32 * 138];     // 8832 B
    int blk = blockIdx.x;                         // 2048 = 16 n * 128 h
    int n = blk >> 7;
    int h = blk & 127;
    int p0 = h * WDIM;                            // one image row
    int t = threadIdx.x;
    int lane = t & 63, wv = t >> 6, gq = lane >> 4, l15 = lane & 15;
    const float* xn = x + (size_t)n * C * HW + p0;

    int lch = t >> 5;                             // 0..7: channel-sub within chunk-j
    int lpx = (t & 31) * 4;                       // 0..124: pixel base (f32x4)

    f32x4 r[4];
    #pragma unroll
    for (int j = 0; j < 4; ++j)
        r[j] = __builtin_nontemporal_load(
            reinterpret_cast<const f32x4*>(&xn[(size_t)(j * 8 + lch) * HW + lpx]));

    f32x4 acc[2][4];
    #pragma unroll
    for (int pt = 0; pt < 2; ++pt)
        #pragma unroll
        for (int m = 0; m < 4; ++m) acc[pt][m] = (f32x4){0.f, 0.f, 0.f, 0.f};

    for (int kc = 0; kc < 8; ++kc) {
        unsigned int pk[4][2];
        #pragma unroll
        for (int j = 0; j < 4; ++j) {
            pk[j][0] = ((unsigned)f2bf(r[j].y) << 16) | f2bf(r[j].x);
            pk[j][1] = ((unsigned)f2bf(r[j].w) << 16) | f2bf(r[j].z);
        }
        __syncthreads();                          // prior chunk's frag reads done
        #pragma unroll
        for (int j = 0; j < 4; ++j) {
            unsigned int* dst = reinterpret_cast<unsigned int*>(
                &xlds[(j * 8 + lch) * 138 + lpx]);
            dst[0] = pk[j][0];
            dst[1] = pk[j][1];
        }
        __syncthreads();                          // tile visible to all waves
        if (kc < 7) {                             // prefetch next chunk early
            #pragma unroll
            for (int j = 0; j < 4; ++j)
                r[j] = __builtin_nontemporal_load(
                    reinterpret_cast<const f32x4*>(
                        &xn[(size_t)((kc + 1) * 32 + j * 8 + lch) * HW + lpx]));
        }
        bf16x8 a[4];
        #pragma unroll
        for (int m = 0; m < 4; ++m)
            a[m] = *reinterpret_cast<const bf16x8*>(cwpk + ((m * 8 + kc) * 64 + lane) * 8);
        #pragma unroll
        for (int pt = 0; pt < 2; ++pt) {
            int px = wv * 32 + pt * 16 + l15;
            union { bf16x8 v; unsigned short u[8]; } b;
            #pragma unroll
            for (int e = 0; e < 8; ++e)
                b.u[e] = xlds[(gq * 8 + e) * 138 + px];
            #pragma unroll
            for (int m = 0; m < 4; ++m)           // SWAPPED: D^T = x^T . w^T
                acc[pt][m] = __builtin_amdgcn_mfma_f32_16x16x32_bf16(b.v, a[m], acc[pt][m], 0, 0, 0);
        }
    }

    // lane now holds: o = m*16 + l15, px = wv*32 + pt*16 + gq*4 + e
    float cbv[4];
    #pragma unroll
    for (int m = 0; m < 4; ++m) cbv[m] = conv_b[m * 16 + l15];

    float cs[4][3];
    #pragma unroll
    for (int m = 0; m < 4; ++m) cs[m][0] = cs[m][1] = cs[m][2] = 0.f;

    unsigned short* fn = f_ws + (size_t)n * C4 * HW;
    #pragma unroll
    for (int pt = 0; pt < 2; ++pt) {
        int pxb = wv * 32 + pt * 16 + gq * 4;
        #pragma unroll
        for (int m = 0; m < 4; ++m) {
            int o = m * 16 + l15;
            union { unsigned int d[2]; unsigned short u[4]; } pk2;
            #pragma unroll
            for (int e = 0; e < 4; ++e) {
                float v = acc[pt][m][e] + cbv[m];
                pk2.u[e] = f2bf(v);
                int px = pxb + e;
                if (px < 43)              cs[m][0] += v;
                if (px >= 42 && px < 86)  cs[m][1] += v;
                if (px >= 85)             cs[m][2] += v;
            }
            *reinterpret_cast<uint2*>(&fn[(size_t)o * HW + p0 + pxb]) =
                (uint2){pk2.d[0], pk2.d[1]};
        }
    }

    // reduce col-bin sums over the 4 gq groups (lanes differ in bits 4-5)
    #pragma unroll
    for (int m = 0; m < 4; ++m)
        #pragma unroll
        for (int b = 0; b < 3; ++b) {
            float v = cs[m][b];
            v += __shfl_xor(v, 16, 64);
            v += __shfl_xor(v, 32, 64);
            cs[m][b] = v;
        }

    if (gq == 0) {
        int hbA = (h < 43) ? 0 : (h < 86 ? 1 : 2);
        int hbB = (h == 42) ? 1 : ((h == 85) ? 2 : -1);
        #pragma unroll
        for (int m = 0; m < 4; ++m) {
            int base = (n * 64 + m * 16 + l15) * 9;
            #pragma unroll
            for (int b = 0; b < 3; ++b) {
                atomicAdd(&gsum[base + hbA * 3 + b], cs[m][b]);
                if (hbB >= 0) atomicAdd(&gsum[base + hbB * 3 + b], cs[m][b]);
            }
        }
    }
}

// ---------------------------------------------------------------------------
// K3: y = depthwise3x3(f, g) ; out = fuse_w . y + fuse_b_eff
// Block: one (n, row h), full 128 cols, 512 threads (8 waves).
// MFMA operand-swapped: D^T = y^T . fuse_w^T, so each lane holds 4
// consecutive pixels of one channel -> f32x4 out-stores (16 dwordx4 vs 64
// dword per thread). g loaded as sums, scaled by 1/(cnt_i*cnt_j) here.
// ---------------------------------------------------------------------------
__global__ __launch_bounds__(512) void k3_dwfuse(
    const unsigned short* __restrict__ f_ws, const float* __restrict__ gsum,
    const unsigned short* __restrict__ fwpk, const float* __restrict__ fbe,
    float* __restrict__ out)
{
    __shared__ unsigned short ylds[64][136];
    int blk = blockIdx.x;                 // 2048
    int n = blk >> 7;
    int h = blk & 127;
    int t = threadIdx.x;

    {   // depthwise: thread t -> channel o = t>>3, strip q = t&7 (16 px)
        const float ginv[9] = {
            1.f/1849.f, 1.f/1892.f, 1.f/1849.f,
            1.f/1892.f, 1.f/1936.f, 1.f/1892.f,
            1.f/1849.f, 1.f/1892.f, 1.f/1849.f };
        int o = t >> 3, q = t & 7;
        int wb = q * 16;
        const unsigned short* fp = f_ws + (size_t)(n * 64 + o) * HW;
        const float* gp = gsum + (n * 64 + o) * 9;
        float gv[9];
        #pragma unroll
        for (int k = 0; k < 9; ++k) gv[k] = gp[k] * ginv[k];
        float y[16];
        #pragma unroll
        for (int i = 0; i < 16; ++i) y[i] = 0.f;
        #pragma unroll
        for (int dy = -1; dy <= 1; ++dy) {
            int hh = h + dy;
            if (hh < 0 || hh >= HDIM) continue;
            const unsigned short* row = fp + hh * WDIM;
            union { uint4 q4; unsigned short u[8]; } bA, bB;
            bA.q4 = *reinterpret_cast<const uint4*>(row + wb);
            bB.q4 = *reinterpret_cast<const uint4*>(row + wb + 8);
            float lft = bf2f(row[wb == 0 ? 0 : wb - 1]);
            if (wb == 0)   lft = 0.f;
            float rgt = bf2f(row[wb == 112 ? 127 : wb + 16]);
            if (wb == 112) rgt = 0.f;
            float rv[18];
            rv[0] = lft;
            #pragma unroll
            for (int z = 0; z < 8; ++z) rv[1 + z] = bf2f(bA.u[z]);
            #pragma unroll
            for (int z = 0; z < 8; ++z) rv[9 + z] = bf2f(bB.u[z]);
            rv[17] = rgt;
            float g0 = gv[(dy + 1) * 3], g1 = gv[(dy + 1) * 3 + 1], g2 = gv[(dy + 1) * 3 + 2];
            #pragma unroll
            for (int i = 0; i < 16; ++i)
                y[i] += g0 * rv[i] + g1 * rv[i + 1] + g2 * rv[i + 2];
        }
        union { uint4 q4[2]; unsigned short u[16]; } pk;
        #pragma unroll
        for (int i = 0; i < 16; ++i) pk.u[i] = f2bf(y[i]);
        *reinterpret_cast<uint4*>(&ylds[o][wb])     = pk.q4[0];
        *reinterpret_cast<uint4*>(&ylds[o][wb + 8]) = pk.q4[1];
    }
    __syncthreads();

    int lane = t & 63, wv = t >> 6, gq = lane >> 4, l15 = lane & 15;
    int chb = (wv & 3) * 64, pxb = (wv >> 2) * 64;
    f32x4 acc[4][4];
    #pragma unroll
    for (int a = 0; a < 4; ++a)
        #pragma unroll
        for (int b = 0; b < 4; ++b) acc[a][b] = (f32x4){0.f,0.f,0.f,0.f};

    #pragma unroll
    for (int kc = 0; kc < 2; ++kc) {
        bf16x8 bfr[4];
        #pragma unroll
        for (int pj = 0; pj < 4; ++pj) {
            union { bf16x8 v; unsigned short u[8]; } bb;
            #pragma unroll
            for (int e = 0; e < 8; ++e)
                bb.u[e] = ylds[kc * 32 + gq * 8 + e][pxb + pj * 16 + l15];
            bfr[pj] = bb.v;
        }
        #pragma unroll
        for (int mc = 0; mc < 4; ++mc) {
            int mtile = (wv & 3) * 4 + mc;
            bf16x8 a = *reinterpret_cast<const bf16x8*>(
                fwpk + ((mtile * 2 + kc) * 64 + lane) * 8);
            #pragma unroll
            for (int pj = 0; pj < 4; ++pj)        // SWAPPED: D^T = y^T . w^T
                acc[mc][pj] = __builtin_amdgcn_mfma_f32_16x16x32_bf16(bfr[pj], a, acc[mc][pj], 0, 0, 0);
        }
    }

    // lane holds: c = chb + mc*16 + l15, px = pxb + pj*16 + gq*4 + e
    size_t outbase = (size_t)n * C * HW + (size_t)h * WDIM;
    #pragma unroll
    for (int mc = 0; mc < 4; ++mc) {
        int c = chb + mc * 16 + l15;
        float bias = fbe[c];
        #pragma unroll
        for (int pj = 0; pj < 4; ++pj) {
            int w = pxb + pj * 16 + gq * 4;
            f32x4 vv;
            #pragma unroll
            for (int e = 0; e < 4; ++e) vv[e] = acc[mc][pj][e] + bias;
            *reinterpret_cast<f32x4*>(&out[outbase + (size_t)c * HW + w]) = vv;
        }
    }
}

// ---------------------------------------------------------------------------
extern "C" void kernel_launch(void* const* d_in, const int* in_sizes, int n_in,
                              void* d_out, int out_size, void* d_ws, size_t ws_size,
                              hipStream_t stream) {
    const float* x      = (const float*)d_in[0];
    const float* conv_w = (const float*)d_in[1];
    const float* conv_b = (const float*)d_in[2];
    const float* dw_b   = (const float*)d_in[3];
    const float* fuse_w = (const float*)d_in[4];
    const float* fuse_b = (const float*)d_in[5];
    float* out = (float*)d_out;

    char* ws = (char*)d_ws;
    unsigned short* f_ws = (unsigned short*)ws;                       // 32 MiB
    float* gsum          = (float*)(ws + 33554432);                   // 36 KiB
    unsigned short* cwpk = (unsigned short*)(ws + 33554432 + 36864);  // 32 KiB
    unsigned short* fwpk = (unsigned short*)(ws + 33554432 + 36864 + 32768);
    float* fbe           = (float*)(ws + 33554432 + 36864 + 32768 + 32768);

    k0_pack<<<dim3(64), dim3(256), 0, stream>>>(conv_w, fuse_w, fuse_b, dw_b, cwpk, fwpk, fbe, gsum);
    k1_conv<<<dim3(2048), dim3(256), 0, stream>>>(x, cwpk, conv_b, f_ws, gsum);
    k3_dwfuse<<<dim3(2048), dim3(512), 0, stream>>>(f_ws, gsum, fwpk, fbe, out);
}

// Round 9
// 150.989 us; speedup vs baseline: 1.7276x; 1.7276x over previous
//
#include <hip/hip_runtime.h>
#include <hip/hip_bf16.h>

#define NB 16
#define C 256
#define C4 64
#define HDIM 128
#define WDIM 128
#define HW 16384

typedef __bf16 bf16x8 __attribute__((ext_vector_type(8)));
typedef float f32x4 __attribute__((ext_vector_type(4)));

__device__ __forceinline__ unsigned short f2bf(float x) {
    union { __bf16 h; unsigned short u; } c;
    c.h = (__bf16)x;                       // RNE
    return c.u;
}
__device__ __forceinline__ float bf2f(unsigned short b) {
    union { float f; unsigned u; } a; a.u = ((unsigned)b) << 16; return a.f;
}

// ---------------------------------------------------------------------------
// K0: pack conv_w (64x256) and fuse_w (256x64) into MFMA fragment order,
// compute fuse_b_eff[c] = fuse_b[c] + sum_o fuse_w[c][o]*dw_b[o].
// Fragment (16x16x32): lane = (i&15) | (((k>>3)&3)<<4), e = k&7. The same
// packed data serves as A-frag of W and B-frag of W^T (layouts are
// transpose-symmetric), which is what lets K1/K3 swap mfma operands freely.
// ---------------------------------------------------------------------------
__global__ __launch_bounds__(256) void k0_pack(
    const float* __restrict__ conv_w, const float* __restrict__ fuse_w,
    const float* __restrict__ fuse_b, const float* __restrict__ dw_b,
    unsigned short* __restrict__ cwpk, unsigned short* __restrict__ fwpk,
    float* __restrict__ fbe)
{
    int tid = blockIdx.x * 256 + threadIdx.x;   // 0..16383
    {   // conv_w: M=64, K=256
        int m = tid >> 8, k = tid & 255;
        int frag = (m >> 4) * 8 + (k >> 5);
        int lane = (m & 15) | (((k >> 3) & 3) << 4);
        int e = k & 7;
        cwpk[(frag * 64 + lane) * 8 + e] = f2bf(conv_w[m * 256 + k]);
    }
    {   // fuse_w: M=256, K=64
        int m = tid >> 6, k = tid & 63;
        int frag = (m >> 4) * 2 + (k >> 5);
        int lane = (m & 15) | (((k >> 3) & 3) << 4);
        int e = k & 7;
        fwpk[(frag * 64 + lane) * 8 + e] = f2bf(fuse_w[m * 64 + k]);
    }
    if (tid < 256) {
        float s = fuse_b[tid];
        #pragma unroll
        for (int o = 0; o < 64; ++o) s += fuse_w[tid * 64 + o] * dw_b[o];
        fbe[tid] = s;
    }
}

// ---------------------------------------------------------------------------
// K1: f = conv1(x) + conv_b  (GEMM, operand-swapped: D^T = x^T . conv_w^T so
// each lane holds 4 CONSECUTIVE PIXELS of one o-channel -> dwordx2 f-stores).
// Pool fusion WITHOUT atomics: each (block, wave) writes its private col-bin
// partial sums to psum[blk][wv][o*3+b] (plain stores, no sharing). k2_reduce
// folds over h and wv. (R8's atomicAdd version caused cross-XCD line
// ping-pong: 196 us, VALUBusy 5%, +50 MB write inflation.)
// ---------------------------------------------------------------------------
__global__ __launch_bounds__(256) void k1_conv(
    const float* __restrict__ x, const unsigned short* __restrict__ cwpk,
    const float* __restrict__ conv_b, unsigned short* __restrict__ f_ws,
    float* __restrict__ psum)
{
    __shared__ unsigned short xlds[32 * 138];     // 8832 B
    int blk = blockIdx.x;                         // 2048 = 16 n * 128 h
    int n = blk >> 7;
    int h = blk & 127;
    int p0 = h * WDIM;                            // one image row
    int t = threadIdx.x;
    int lane = t & 63, wv = t >> 6, gq = lane >> 4, l15 = lane & 15;
    const float* xn = x + (size_t)n * C * HW + p0;

    int lch = t >> 5;                             // 0..7: channel-sub within chunk-j
    int lpx = (t & 31) * 4;                       // 0..124: pixel base (f32x4)

    f32x4 r[4];
    #pragma unroll
    for (int j = 0; j < 4; ++j)
        r[j] = __builtin_nontemporal_load(
            reinterpret_cast<const f32x4*>(&xn[(size_t)(j * 8 + lch) * HW + lpx]));

    f32x4 acc[2][4];
    #pragma unroll
    for (int pt = 0; pt < 2; ++pt)
        #pragma unroll
        for (int m = 0; m < 4; ++m) acc[pt][m] = (f32x4){0.f, 0.f, 0.f, 0.f};

    for (int kc = 0; kc < 8; ++kc) {
        unsigned int pk[4][2];
        #pragma unroll
        for (int j = 0; j < 4; ++j) {
            pk[j][0] = ((unsigned)f2bf(r[j].y) << 16) | f2bf(r[j].x);
            pk[j][1] = ((unsigned)f2bf(r[j].w) << 16) | f2bf(r[j].z);
        }
        __syncthreads();                          // prior chunk's frag reads done
        #pragma unroll
        for (int j = 0; j < 4; ++j) {
            unsigned int* dst = reinterpret_cast<unsigned int*>(
                &xlds[(j * 8 + lch) * 138 + lpx]);
            dst[0] = pk[j][0];
            dst[1] = pk[j][1];
        }
        __syncthreads();                          // tile visible to all waves
        if (kc < 7) {                             // prefetch next chunk early
            #pragma unroll
            for (int j = 0; j < 4; ++j)
                r[j] = __builtin_nontemporal_load(
                    reinterpret_cast<const f32x4*>(
                        &xn[(size_t)((kc + 1) * 32 + j * 8 + lch) * HW + lpx]));
        }
        bf16x8 a[4];
        #pragma unroll
        for (int m = 0; m < 4; ++m)
            a[m] = *reinterpret_cast<const bf16x8*>(cwpk + ((m * 8 + kc) * 64 + lane) * 8);
        #pragma unroll
        for (int pt = 0; pt < 2; ++pt) {
            int px = wv * 32 + pt * 16 + l15;
            union { bf16x8 v; unsigned short u[8]; } b;
            #pragma unroll
            for (int e = 0; e < 8; ++e)
                b.u[e] = xlds[(gq * 8 + e) * 138 + px];
            #pragma unroll
            for (int m = 0; m < 4; ++m)           // SWAPPED: D^T = x^T . w^T
                acc[pt][m] = __builtin_amdgcn_mfma_f32_16x16x32_bf16(b.v, a[m], acc[pt][m], 0, 0, 0);
        }
    }

    // lane now holds: o = m*16 + l15, px = wv*32 + pt*16 + gq*4 + e
    float cbv[4];
    #pragma unroll
    for (int m = 0; m < 4; ++m) cbv[m] = conv_b[m * 16 + l15];

    float cs[4][3];
    #pragma unroll
    for (int m = 0; m < 4; ++m) cs[m][0] = cs[m][1] = cs[m][2] = 0.f;

    unsigned short* fn = f_ws + (size_t)n * C4 * HW;
    #pragma unroll
    for (int pt = 0; pt < 2; ++pt) {
        int pxb = wv * 32 + pt * 16 + gq * 4;
        #pragma unroll
        for (int m = 0; m < 4; ++m) {
            int o = m * 16 + l15;
            union { unsigned int d[2]; unsigned short u[4]; } pk2;
            #pragma unroll
            for (int e = 0; e < 4; ++e) {
                float v = acc[pt][m][e] + cbv[m];
                pk2.u[e] = f2bf(v);
                int px = pxb + e;
                if (px < 43)              cs[m][0] += v;
                if (px >= 42 && px < 86)  cs[m][1] += v;
                if (px >= 85)             cs[m][2] += v;
            }
            *reinterpret_cast<uint2*>(&fn[(size_t)o * HW + p0 + pxb]) =
                (uint2){pk2.d[0], pk2.d[1]};
        }
    }

    // reduce col-bin sums over the 4 gq groups (lanes differ in bits 4-5);
    // each wave covers 32 pixels, so waves hold partials -> psum per (blk,wv)
    #pragma unroll
    for (int m = 0; m < 4; ++m)
        #pragma unroll
        for (int b = 0; b < 3; ++b) {
            float v = cs[m][b];
            v += __shfl_xor(v, 16, 64);
            v += __shfl_xor(v, 32, 64);
            cs[m][b] = v;
        }

    if (gq == 0) {
        float* ps = psum + ((size_t)blk * 4 + wv) * 192;
        #pragma unroll
        for (int m = 0; m < 4; ++m)
            #pragma unroll
            for (int b = 0; b < 3; ++b)
                ps[(m * 16 + l15) * 3 + b] = cs[m][b];
    }
}

// ---------------------------------------------------------------------------
// K2r: gsum[n,o,i,j] = sum over h (with torch-adaptive h-bin overlap) and wv
// of psum. 16 blocks x 192 threads; reads 6.3 MB (L2-resident), ~3 us.
// ---------------------------------------------------------------------------
__global__ __launch_bounds__(192) void k2_reduce(
    const float* __restrict__ psum, float* __restrict__ gsum)
{
    int n = blockIdx.x;                 // 16
    int t = threadIdx.x;                // 0..191 = o*3 + cb
    int o = t / 3, cb = t - 3 * o;
    const float* ps = psum + (size_t)n * 128 * 768 + t;
    float s0 = 0.f, s1 = 0.f, s2 = 0.f;
    for (int h = 0; h < 128; ++h) {
        float v = 0.f;
        #pragma unroll
        for (int wv = 0; wv < 4; ++wv) v += ps[h * 768 + wv * 192];
        if (h < 43)            s0 += v;
        if (h >= 42 && h < 86) s1 += v;
        if (h >= 85)           s2 += v;
    }
    float* gp = gsum + (n * 64 + o) * 9;
    gp[0 + cb] = s0;
    gp[3 + cb] = s1;
    gp[6 + cb] = s2;
}

// ---------------------------------------------------------------------------
// K3: y = depthwise3x3(f, g) ; out = fuse_w . y + fuse_b_eff
// Block: one (n, row h), full 128 cols, 512 threads (8 waves).
// MFMA operand-swapped: D^T = y^T . fuse_w^T, so each lane holds 4
// consecutive pixels of one channel -> f32x4 out-stores (16 dwordx4, each
// covering 16 full 64B lines). g loaded as raw sums, scaled here.
// ---------------------------------------------------------------------------
__global__ __launch_bounds__(512) void k3_dwfuse(
    const unsigned short* __restrict__ f_ws, const float* __restrict__ gsum,
    const unsigned short* __restrict__ fwpk, const float* __restrict__ fbe,
    float* __restrict__ out)
{
    __shared__ unsigned short ylds[64][136];
    int blk = blockIdx.x;                 // 2048
    int n = blk >> 7;
    int h = blk & 127;
    int t = threadIdx.x;

    {   // depthwise: thread t -> channel o = t>>3, strip q = t&7 (16 px)
        const float ginv[9] = {
            1.f/1849.f, 1.f/1892.f, 1.f/1849.f,
            1.f/1892.f, 1.f/1936.f, 1.f/1892.f,
            1.f/1849.f, 1.f/1892.f, 1.f/1849.f };
        int o = t >> 3, q = t & 7;
        int wb = q * 16;
        const unsigned short* fp = f_ws + (size_t)(n * 64 + o) * HW;
        const float* gp = gsum + (n * 64 + o) * 9;
        float gv[9];
        #pragma unroll
        for (int k = 0; k < 9; ++k) gv[k] = gp[k] * ginv[k];
        float y[16];
        #pragma unroll
        for (int i = 0; i < 16; ++i) y[i] = 0.f;
        #pragma unroll
        for (int dy = -1; dy <= 1; ++dy) {
            int hh = h + dy;
            if (hh < 0 || hh >= HDIM) continue;
            const unsigned short* row = fp + hh * WDIM;
            union { uint4 q4; unsigned short u[8]; } bA, bB;
            bA.q4 = *reinterpret_cast<const uint4*>(row + wb);
            bB.q4 = *reinterpret_cast<const uint4*>(row + wb + 8);
            float lft = bf2f(row[wb == 0 ? 0 : wb - 1]);
            if (wb == 0)   lft = 0.f;
            float rgt = bf2f(row[wb == 112 ? 127 : wb + 16]);
            if (wb == 112) rgt = 0.f;
            float rv[18];
            rv[0] = lft;
            #pragma unroll
            for (int z = 0; z < 8; ++z) rv[1 + z] = bf2f(bA.u[z]);
            #pragma unroll
            for (int z = 0; z < 8; ++z) rv[9 + z] = bf2f(bB.u[z]);
            rv[17] = rgt;
            float g0 = gv[(dy + 1) * 3], g1 = gv[(dy + 1) * 3 + 1], g2 = gv[(dy + 1) * 3 + 2];
            #pragma unroll
            for (int i = 0; i < 16; ++i)
                y[i] += g0 * rv[i] + g1 * rv[i + 1] + g2 * rv[i + 2];
        }
        union { uint4 q4[2]; unsigned short u[16]; } pk;
        #pragma unroll
        for (int i = 0; i < 16; ++i) pk.u[i] = f2bf(y[i]);
        *reinterpret_cast<uint4*>(&ylds[o][wb])     = pk.q4[0];
        *reinterpret_cast<uint4*>(&ylds[o][wb + 8]) = pk.q4[1];
    }
    __syncthreads();

    int lane = t & 63, wv = t >> 6, gq = lane >> 4, l15 = lane & 15;
    int chb = (wv & 3) * 64, pxb = (wv >> 2) * 64;
    f32x4 acc[4][4];
    #pragma unroll
    for (int a = 0; a < 4; ++a)
        #pragma unroll
        for (int b = 0; b < 4; ++b) acc[a][b] = (f32x4){0.f,0.f,0.f,0.f};

    #pragma unroll
    for (int kc = 0; kc < 2; ++kc) {
        bf16x8 bfr[4];
        #pragma unroll
        for (int pj = 0; pj < 4; ++pj) {
            union { bf16x8 v; unsigned short u[8]; } bb;
            #pragma unroll
            for (int e = 0; e < 8; ++e)
                bb.u[e] = ylds[kc * 32 + gq * 8 + e][pxb + pj * 16 + l15];
            bfr[pj] = bb.v;
        }
        #pragma unroll
        for (int mc = 0; mc < 4; ++mc) {
            int mtile = (wv & 3) * 4 + mc;
            bf16x8 a = *reinterpret_cast<const bf16x8*>(
                fwpk + ((mtile * 2 + kc) * 64 + lane) * 8);
            #pragma unroll
            for (int pj = 0; pj < 4; ++pj)        // SWAPPED: D^T = y^T . w^T
                acc[mc][pj] = __builtin_amdgcn_mfma_f32_16x16x32_bf16(bfr[pj], a, acc[mc][pj], 0, 0, 0);
        }
    }

    // lane holds: c = chb + mc*16 + l15, px = pxb + pj*16 + gq*4 + e
    size_t outbase = (size_t)n * C * HW + (size_t)h * WDIM;
    #pragma unroll
    for (int mc = 0; mc < 4; ++mc) {
        int c = chb + mc * 16 + l15;
        float bias = fbe[c];
        #pragma unroll
        for (int pj = 0; pj < 4; ++pj) {
            int w = pxb + pj * 16 + gq * 4;
            f32x4 vv;
            #pragma unroll
            for (int e = 0; e < 4; ++e) vv[e] = acc[mc][pj][e] + bias;
            *reinterpret_cast<f32x4*>(&out[outbase + (size_t)c * HW + w]) = vv;
        }
    }
}

// ---------------------------------------------------------------------------
extern "C" void kernel_launch(void* const* d_in, const int* in_sizes, int n_in,
                              void* d_out, int out_size, void* d_ws, size_t ws_size,
                              hipStream_t stream) {
    const float* x      = (const float*)d_in[0];
    const float* conv_w = (const float*)d_in[1];
    const float* conv_b = (const float*)d_in[2];
    const float* dw_b   = (const float*)d_in[3];
    const float* fuse_w = (const float*)d_in[4];
    const float* fuse_b = (const float*)d_in[5];
    float* out = (float*)d_out;

    char* ws = (char*)d_ws;
    unsigned short* f_ws = (unsigned short*)ws;                      // 32 MiB
    float* psum          = (float*)(ws + 33554432);                  // 6 MiB
    float* gsum          = (float*)(ws + 33554432 + 6291456);        // 36 KiB
    unsigned short* cwpk = (unsigned short*)(ws + 33554432 + 6291456 + 36864);
    unsigned short* fwpk = (unsigned short*)(ws + 33554432 + 6291456 + 36864 + 32768);
    float* fbe           = (float*)(ws + 33554432 + 6291456 + 36864 + 32768 + 32768);

    k0_pack<<<dim3(64), dim3(256), 0, stream>>>(conv_w, fuse_w, fuse_b, dw_b, cwpk, fwpk, fbe);
    k1_conv<<<dim3(2048), dim3(256), 0, stream>>>(x, cwpk, conv_b, f_ws, psum);
    k2_reduce<<<dim3(16), dim3(192), 0, stream>>>(psum, gsum);
    k3_dwfuse<<<dim3(2048), dim3(512), 0, stream>>>(f_ws, gsum, fwpk, fbe, out);
}

// Round 10
// 138.210 us; speedup vs baseline: 1.8873x; 1.0925x over previous
//
#include <hip/hip_runtime.h>
#include <hip/hip_bf16.h>

#define NB 16
#define C 256
#define C4 64
#define HDIM 128
#define WDIM 128
#define HW 16384

typedef __bf16 bf16x8 __attribute__((ext_vector_type(8)));
typedef float f32x4 __attribute__((ext_vector_type(4)));

__device__ __forceinline__ unsigned short f2bf(float x) {
    union { __bf16 h; unsigned short u; } c;
    c.h = (__bf16)x;                       // RNE
    return c.u;
}
__device__ __forceinline__ float bf2f(unsigned short b) {
    union { float f; unsigned u; } a; a.u = ((unsigned)b) << 16; return a.f;
}

// ---------------------------------------------------------------------------
// K0: pack conv_w (64x256) and fuse_w (256x64) into MFMA fragment order,
// compute fuse_b_eff[c] = fuse_b[c] + sum_o fuse_w[c][o]*dw_b[o].
// Fragment (16x16x32): lane = (i&15) | (((k>>3)&3)<<4), e = k&7. The same
// packed data serves as A-frag of W and B-frag of W^T (layouts are
// transpose-symmetric), which is what lets K1/K3 swap mfma operands freely.
// ---------------------------------------------------------------------------
__global__ __launch_bounds__(256) void k0_pack(
    const float* __restrict__ conv_w, const float* __restrict__ fuse_w,
    const float* __restrict__ fuse_b, const float* __restrict__ dw_b,
    unsigned short* __restrict__ cwpk, unsigned short* __restrict__ fwpk,
    float* __restrict__ fbe)
{
    int tid = blockIdx.x * 256 + threadIdx.x;   // 0..16383
    {   // conv_w: M=64, K=256
        int m = tid >> 8, k = tid & 255;
        int frag = (m >> 4) * 8 + (k >> 5);
        int lane = (m & 15) | (((k >> 3) & 3) << 4);
        int e = k & 7;
        cwpk[(frag * 64 + lane) * 8 + e] = f2bf(conv_w[m * 256 + k]);
    }
    {   // fuse_w: M=256, K=64
        int m = tid >> 6, k = tid & 63;
        int frag = (m >> 4) * 2 + (k >> 5);
        int lane = (m & 15) | (((k >> 3) & 3) << 4);
        int e = k & 7;
        fwpk[(frag * 64 + lane) * 8 + e] = f2bf(fuse_w[m * 64 + k]);
    }
    if (tid < 256) {
        float s = fuse_b[tid];
        #pragma unroll
        for (int o = 0; o < 64; ++o) s += fuse_w[tid * 64 + o] * dw_b[o];
        fbe[tid] = s;
    }
}

// ---------------------------------------------------------------------------
// K1: f = conv1(x) + conv_b  (GEMM, operand-swapped: D^T = x^T . conv_w^T so
// each lane holds 4 CONSECUTIVE PIXELS of one o-channel -> dwordx2 f-stores).
// Pool fusion, no atomics: per-wave col-bin partials are combined across the
// 4 waves in LDS, then ONE contiguous 192-float row per block goes to psum
// (1.57 MB total). k2_reduce (1024 blocks) folds h and the h-bin overlap.
// ---------------------------------------------------------------------------
__global__ __launch_bounds__(256) void k1_conv(
    const float* __restrict__ x, const unsigned short* __restrict__ cwpk,
    const float* __restrict__ conv_b, unsigned short* __restrict__ f_ws,
    float* __restrict__ psum)
{
    __shared__ unsigned short xlds[32 * 138];     // 8832 B
    __shared__ float xpool[4][192];               // 3072 B
    int blk = blockIdx.x;                         // 2048 = 16 n * 128 h
    int n = blk >> 7;
    int h = blk & 127;
    int p0 = h * WDIM;                            // one image row
    int t = threadIdx.x;
    int lane = t & 63, wv = t >> 6, gq = lane >> 4, l15 = lane & 15;
    const float* xn = x + (size_t)n * C * HW + p0;

    int lch = t >> 5;                             // 0..7: channel-sub within chunk-j
    int lpx = (t & 31) * 4;                       // 0..124: pixel base (f32x4)

    f32x4 r[4];
    #pragma unroll
    for (int j = 0; j < 4; ++j)
        r[j] = __builtin_nontemporal_load(
            reinterpret_cast<const f32x4*>(&xn[(size_t)(j * 8 + lch) * HW + lpx]));

    f32x4 acc[2][4];
    #pragma unroll
    for (int pt = 0; pt < 2; ++pt)
        #pragma unroll
        for (int m = 0; m < 4; ++m) acc[pt][m] = (f32x4){0.f, 0.f, 0.f, 0.f};

    for (int kc = 0; kc < 8; ++kc) {
        unsigned int pk[4][2];
        #pragma unroll
        for (int j = 0; j < 4; ++j) {
            pk[j][0] = ((unsigned)f2bf(r[j].y) << 16) | f2bf(r[j].x);
            pk[j][1] = ((unsigned)f2bf(r[j].w) << 16) | f2bf(r[j].z);
        }
        __syncthreads();                          // prior chunk's frag reads done
        #pragma unroll
        for (int j = 0; j < 4; ++j) {
            unsigned int* dst = reinterpret_cast<unsigned int*>(
                &xlds[(j * 8 + lch) * 138 + lpx]);
            dst[0] = pk[j][0];
            dst[1] = pk[j][1];
        }
        __syncthreads();                          // tile visible to all waves
        if (kc < 7) {                             // prefetch next chunk early
            #pragma unroll
            for (int j = 0; j < 4; ++j)
                r[j] = __builtin_nontemporal_load(
                    reinterpret_cast<const f32x4*>(
                        &xn[(size_t)((kc + 1) * 32 + j * 8 + lch) * HW + lpx]));
        }
        bf16x8 a[4];
        #pragma unroll
        for (int m = 0; m < 4; ++m)
            a[m] = *reinterpret_cast<const bf16x8*>(cwpk + ((m * 8 + kc) * 64 + lane) * 8);
        #pragma unroll
        for (int pt = 0; pt < 2; ++pt) {
            int px = wv * 32 + pt * 16 + l15;
            union { bf16x8 v; unsigned short u[8]; } b;
            #pragma unroll
            for (int e = 0; e < 8; ++e)
                b.u[e] = xlds[(gq * 8 + e) * 138 + px];
            #pragma unroll
            for (int m = 0; m < 4; ++m)           // SWAPPED: D^T = x^T . w^T
                acc[pt][m] = __builtin_amdgcn_mfma_f32_16x16x32_bf16(b.v, a[m], acc[pt][m], 0, 0, 0);
        }
    }

    // lane now holds: o = m*16 + l15, px = wv*32 + pt*16 + gq*4 + e
    float cbv[4];
    #pragma unroll
    for (int m = 0; m < 4; ++m) cbv[m] = conv_b[m * 16 + l15];

    float cs[4][3];
    #pragma unroll
    for (int m = 0; m < 4; ++m) cs[m][0] = cs[m][1] = cs[m][2] = 0.f;

    unsigned short* fn = f_ws + (size_t)n * C4 * HW;
    #pragma unroll
    for (int pt = 0; pt < 2; ++pt) {
        int pxb = wv * 32 + pt * 16 + gq * 4;
        #pragma unroll
        for (int m = 0; m < 4; ++m) {
            int o = m * 16 + l15;
            union { unsigned int d[2]; unsigned short u[4]; } pk2;
            #pragma unroll
            for (int e = 0; e < 4; ++e) {
                float v = acc[pt][m][e] + cbv[m];
                pk2.u[e] = f2bf(v);
                int px = pxb + e;
                if (px < 43)              cs[m][0] += v;
                if (px >= 42 && px < 86)  cs[m][1] += v;
                if (px >= 85)             cs[m][2] += v;
            }
            *reinterpret_cast<uint2*>(&fn[(size_t)o * HW + p0 + pxb]) =
                (uint2){pk2.d[0], pk2.d[1]};
        }
    }

    // reduce col-bin sums over the 4 gq groups (lanes differ in bits 4-5)
    #pragma unroll
    for (int m = 0; m < 4; ++m)
        #pragma unroll
        for (int b = 0; b < 3; ++b) {
            float v = cs[m][b];
            v += __shfl_xor(v, 16, 64);
            v += __shfl_xor(v, 32, 64);
            cs[m][b] = v;
        }

    if (gq == 0) {
        #pragma unroll
        for (int m = 0; m < 4; ++m)
            #pragma unroll
            for (int b = 0; b < 3; ++b)
                xpool[wv][(m * 16 + l15) * 3 + b] = cs[m][b];
    }
    __syncthreads();
    if (t < 192)
        psum[(size_t)blk * 192 + t] =
            xpool[0][t] + xpool[1][t] + xpool[2][t] + xpool[3][t];
}

// ---------------------------------------------------------------------------
// K2r: gsum[n,o,i,j] = sum over h (with torch-adaptive h-bin overlap: rows
// 42 & 85 belong to two bins) of psum[n*128+h][o*3+b].
// 1024 blocks (one per (n,o)) x 128 threads (one per h) -> fully parallel,
// ~2 us. (R9's 16-block version was a latency-bound ~10-15 us tail.)
// ---------------------------------------------------------------------------
__global__ __launch_bounds__(128) void k2_reduce(
    const float* __restrict__ psum, float* __restrict__ gsum)
{
    int bid = blockIdx.x;               // 1024
    int n = bid >> 6, o = bid & 63;
    int h = threadIdx.x;                // 0..127
    const float* ps = psum + ((size_t)(n * 128 + h)) * 192 + o * 3;
    float v0 = ps[0], v1 = ps[1], v2 = ps[2];

    float s[9];
    #pragma unroll
    for (int k = 0; k < 9; ++k) s[k] = 0.f;
    if (h < 43)            { s[0] += v0; s[1] += v1; s[2] += v2; }
    if (h >= 42 && h < 86) { s[3] += v0; s[4] += v1; s[5] += v2; }
    if (h >= 85)           { s[6] += v0; s[7] += v1; s[8] += v2; }

    int lane = h & 63, wid = h >> 6;
    #pragma unroll
    for (int k = 0; k < 9; ++k) {
        float v = s[k];
        for (int off = 32; off > 0; off >>= 1) v += __shfl_down(v, off, 64);
        s[k] = v;
    }
    __shared__ float red[2][9];
    if (lane == 0) {
        #pragma unroll
        for (int k = 0; k < 9; ++k) red[wid][k] = s[k];
    }
    __syncthreads();
    if (threadIdx.x < 9)
        gsum[(n * 64 + o) * 9 + threadIdx.x] = red[0][threadIdx.x] + red[1][threadIdx.x];
}

// ---------------------------------------------------------------------------
// K3: y = depthwise3x3(f, g) ; out = fuse_w . y + fuse_b_eff
// Block: one (n, row h), full 128 cols, 512 threads (8 waves).
// MFMA operand-swapped: D^T = y^T . fuse_w^T, so each lane holds 4
// consecutive pixels of one channel -> f32x4 out-stores. g loaded as raw
// sums, scaled by 1/(cnt_i*cnt_j) here.
// ---------------------------------------------------------------------------
__global__ __launch_bounds__(512) void k3_dwfuse(
    const unsigned short* __restrict__ f_ws, const float* __restrict__ gsum,
    const unsigned short* __restrict__ fwpk, const float* __restrict__ fbe,
    float* __restrict__ out)
{
    __shared__ unsigned short ylds[64][136];
    int blk = blockIdx.x;                 // 2048
    int n = blk >> 7;
    int h = blk & 127;
    int t = threadIdx.x;

    {   // depthwise: thread t -> channel o = t>>3, strip q = t&7 (16 px)
        const float ginv[9] = {
            1.f/1849.f, 1.f/1892.f, 1.f/1849.f,
            1.f/1892.f, 1.f/1936.f, 1.f/1892.f,
            1.f/1849.f, 1.f/1892.f, 1.f/1849.f };
        int o = t >> 3, q = t & 7;
        int wb = q * 16;
        const unsigned short* fp = f_ws + (size_t)(n * 64 + o) * HW;
        const float* gp = gsum + (n * 64 + o) * 9;
        float gv[9];
        #pragma unroll
        for (int k = 0; k < 9; ++k) gv[k] = gp[k] * ginv[k];
        float y[16];
        #pragma unroll
        for (int i = 0; i < 16; ++i) y[i] = 0.f;
        #pragma unroll
        for (int dy = -1; dy <= 1; ++dy) {
            int hh = h + dy;
            if (hh < 0 || hh >= HDIM) continue;
            const unsigned short* row = fp + hh * WDIM;
            union { uint4 q4; unsigned short u[8]; } bA, bB;
            bA.q4 = *reinterpret_cast<const uint4*>(row + wb);
            bB.q4 = *reinterpret_cast<const uint4*>(row + wb + 8);
            float lft = bf2f(row[wb == 0 ? 0 : wb - 1]);
            if (wb == 0)   lft = 0.f;
            float rgt = bf2f(row[wb == 112 ? 127 : wb + 16]);
            if (wb == 112) rgt = 0.f;
            float rv[18];
            rv[0] = lft;
            #pragma unroll
            for (int z = 0; z < 8; ++z) rv[1 + z] = bf2f(bA.u[z]);
            #pragma unroll
            for (int z = 0; z < 8; ++z) rv[9 + z] = bf2f(bB.u[z]);
            rv[17] = rgt;
            float g0 = gv[(dy + 1) * 3], g1 = gv[(dy + 1) * 3 + 1], g2 = gv[(dy + 1) * 3 + 2];
            #pragma unroll
            for (int i = 0; i < 16; ++i)
                y[i] += g0 * rv[i] + g1 * rv[i + 1] + g2 * rv[i + 2];
        }
        union { uint4 q4[2]; unsigned short u[16]; } pk;
        #pragma unroll
        for (int i = 0; i < 16; ++i) pk.u[i] = f2bf(y[i]);
        *reinterpret_cast<uint4*>(&ylds[o][wb])     = pk.q4[0];
        *reinterpret_cast<uint4*>(&ylds[o][wb + 8]) = pk.q4[1];
    }
    __syncthreads();

    int lane = t & 63, wv = t >> 6, gq = lane >> 4, l15 = lane & 15;
    int chb = (wv & 3) * 64, pxb = (wv >> 2) * 64;
    f32x4 acc[4][4];
    #pragma unroll
    for (int a = 0; a < 4; ++a)
        #pragma unroll
        for (int b = 0; b < 4; ++b) acc[a][b] = (f32x4){0.f,0.f,0.f,0.f};

    #pragma unroll
    for (int kc = 0; kc < 2; ++kc) {
        bf16x8 bfr[4];
        #pragma unroll
        for (int pj = 0; pj < 4; ++pj) {
            union { bf16x8 v; unsigned short u[8]; } bb;
            #pragma unroll
            for (int e = 0; e < 8; ++e)
                bb.u[e] = ylds[kc * 32 + gq * 8 + e][pxb + pj * 16 + l15];
            bfr[pj] = bb.v;
        }
        #pragma unroll
        for (int mc = 0; mc < 4; ++mc) {
            int mtile = (wv & 3) * 4 + mc;
            bf16x8 a = *reinterpret_cast<const bf16x8*>(
                fwpk + ((mtile * 2 + kc) * 64 + lane) * 8);
            #pragma unroll
            for (int pj = 0; pj < 4; ++pj)        // SWAPPED: D^T = y^T . w^T
                acc[mc][pj] = __builtin_amdgcn_mfma_f32_16x16x32_bf16(bfr[pj], a, acc[mc][pj], 0, 0, 0);
        }
    }

    // lane holds: c = chb + mc*16 + l15, px = pxb + pj*16 + gq*4 + e
    size_t outbase = (size_t)n * C * HW + (size_t)h * WDIM;
    #pragma unroll
    for (int mc = 0; mc < 4; ++mc) {
        int c = chb + mc * 16 + l15;
        float bias = fbe[c];
        #pragma unroll
        for (int pj = 0; pj < 4; ++pj) {
            int w = pxb + pj * 16 + gq * 4;
            f32x4 vv;
            #pragma unroll
            for (int e = 0; e < 4; ++e) vv[e] = acc[mc][pj][e] + bias;
            *reinterpret_cast<f32x4*>(&out[outbase + (size_t)c * HW + w]) = vv;
        }
    }
}

// ---------------------------------------------------------------------------
extern "C" void kernel_launch(void* const* d_in, const int* in_sizes, int n_in,
                              void* d_out, int out_size, void* d_ws, size_t ws_size,
                              hipStream_t stream) {
    const float* x      = (const float*)d_in[0];
    const float* conv_w = (const float*)d_in[1];
    const float* conv_b = (const float*)d_in[2];
    const float* dw_b   = (const float*)d_in[3];
    const float* fuse_w = (const float*)d_in[4];
    const float* fuse_b = (const float*)d_in[5];
    float* out = (float*)d_out;

    char* ws = (char*)d_ws;
    unsigned short* f_ws = (unsigned short*)ws;                      // 32 MiB
    float* psum          = (float*)(ws + 33554432);                  // 1.57 MiB
    float* gsum          = (float*)(ws + 33554432 + 2097152);        // 36 KiB
    unsigned short* cwpk = (unsigned short*)(ws + 33554432 + 2097152 + 36864);
    unsigned short* fwpk = (unsigned short*)(ws + 33554432 + 2097152 + 36864 + 32768);
    float* fbe           = (float*)(ws + 33554432 + 2097152 + 36864 + 32768 + 32768);

    k0_pack<<<dim3(64), dim3(256), 0, stream>>>(conv_w, fuse_w, fuse_b, dw_b, cwpk, fwpk, fbe);
    k1_conv<<<dim3(2048), dim3(256), 0, stream>>>(x, cwpk, conv_b, f_ws, psum);
    k2_reduce<<<dim3(1024), dim3(128), 0, stream>>>(psum, gsum);
    k3_dwfuse<<<dim3(2048), dim3(512), 0, stream>>>(f_ws, gsum, fwpk, fbe, out);
}